// Round 2
// baseline (730.309 us; speedup 1.0000x reference)
//
#include <hip/hip_runtime.h>
#include <math.h>

#define B 32
#define NF 128
#define DE 256
#define DH 512
#define G 2
#define SL 8

// ---------------------------------------------------------------------------
// K1: query[b,d] = dot(c_i[b,:], map_c_w[d,:]) + map_c_b[d]
// One wave per output (8192 waves). 512 = 64 lanes x 8 floats (2x float4).
// ---------------------------------------------------------------------------
__global__ __launch_bounds__(256) void k_query(const float* __restrict__ c_i,
                                               const float* __restrict__ w,
                                               const float* __restrict__ bias,
                                               float* __restrict__ query) {
    const int wave = blockIdx.x * 4 + (threadIdx.x >> 6);
    const int lane = threadIdx.x & 63;
    const int b = wave >> 8;   // 256 outputs (d) per batch
    const int d = wave & 255;
    const float4* cv = (const float4*)(c_i + (size_t)b * DH);
    const float4* wv = (const float4*)(w + (size_t)d * DH);
    float4 a0 = cv[lane];
    float4 b0 = wv[lane];
    float4 a1 = cv[64 + lane];
    float4 b1 = wv[64 + lane];
    float acc = a0.x * b0.x + a0.y * b0.y + a0.z * b0.z + a0.w * b0.w
              + a1.x * b1.x + a1.y * b1.y + a1.z * b1.z + a1.w * b1.w;
    #pragma unroll
    for (int m = 32; m; m >>= 1) acc += __shfl_xor(acc, m, 64);
    if (lane == 0) query[wave] = acc + bias[d];
}

// ---------------------------------------------------------------------------
// K2: P = M @ M (per batch). Block = 16 rows of one batch; full M in LDS.
// grid = 32 batches * 8 row-blocks = 256 blocks.
// ---------------------------------------------------------------------------
__global__ __launch_bounds__(256) void k_msq(const float* __restrict__ rm,
                                             float* __restrict__ P) {
    __shared__ float Ms[NF * NF];          // 64 KiB
    const int b  = blockIdx.x >> 3;
    const int i0 = (blockIdx.x & 7) * 16;
    const int t  = threadIdx.x;
    const float4* src = (const float4*)(rm + (size_t)b * NF * NF);
    float4* dst = (float4*)Ms;
    for (int idx = t; idx < NF * NF / 4; idx += 256) dst[idx] = src[idx];
    __syncthreads();
    const int j  = t & 127;
    const int ig = t >> 7;                 // 0 or 1
    const int ibase = i0 + ig * 8;         // 8 rows per thread
    float acc[8] = {0, 0, 0, 0, 0, 0, 0, 0};
    for (int k = 0; k < NF; k += 4) {
        const float b0 = Ms[(k + 0) * NF + j];
        const float b1 = Ms[(k + 1) * NF + j];
        const float b2 = Ms[(k + 2) * NF + j];
        const float b3 = Ms[(k + 3) * NF + j];
        #pragma unroll
        for (int r = 0; r < 8; ++r) {
            const float4 a = *(const float4*)(Ms + (ibase + r) * NF + k);
            acc[r] += a.x * b0 + a.y * b1 + a.z * b2 + a.w * b3;
        }
    }
    float* Pb = P + (size_t)b * NF * NF;
    #pragma unroll
    for (int r = 0; r < 8; ++r) Pb[(ibase + r) * NF + j] = acc[r];
}

// ---------------------------------------------------------------------------
// K3: F = M + 0.9*P + P @ (0.81*M + 0.729*P)        (P = M^2)
//   = M + 0.9M^2 + 0.81M^3 + 0.729M^4
// ---------------------------------------------------------------------------
__global__ __launch_bounds__(256) void k_final(const float* __restrict__ rm,
                                               const float* __restrict__ P,
                                               float* __restrict__ F) {
    __shared__ float Cs[NF * NF];          // 64 KiB
    const int b  = blockIdx.x >> 3;
    const int i0 = (blockIdx.x & 7) * 16;
    const int t  = threadIdx.x;
    const float* Mb = rm + (size_t)b * NF * NF;
    const float* Pb = P + (size_t)b * NF * NF;
    const float4* mv = (const float4*)Mb;
    const float4* pv = (const float4*)Pb;
    float4* cs4 = (float4*)Cs;
    for (int idx = t; idx < NF * NF / 4; idx += 256) {
        float4 m4 = mv[idx], p4 = pv[idx], c;
        c.x = 0.81f * m4.x + 0.729f * p4.x;
        c.y = 0.81f * m4.y + 0.729f * p4.y;
        c.z = 0.81f * m4.z + 0.729f * p4.z;
        c.w = 0.81f * m4.w + 0.729f * p4.w;
        cs4[idx] = c;
    }
    __syncthreads();
    const int j  = t & 127;
    const int ig = t >> 7;
    const int ibase = i0 + ig * 8;
    float acc[8] = {0, 0, 0, 0, 0, 0, 0, 0};
    for (int k = 0; k < NF; k += 4) {
        const float b0 = Cs[(k + 0) * NF + j];
        const float b1 = Cs[(k + 1) * NF + j];
        const float b2 = Cs[(k + 2) * NF + j];
        const float b3 = Cs[(k + 3) * NF + j];
        #pragma unroll
        for (int r = 0; r < 8; ++r) {
            const float4 a = *(const float4*)(Pb + (size_t)(ibase + r) * NF + k);
            acc[r] += a.x * b0 + a.y * b1 + a.z * b2 + a.w * b3;
        }
    }
    float* Fb = F + (size_t)b * NF * NF;
    #pragma unroll
    for (int r = 0; r < 8; ++r) {
        const int i = ibase + r;
        Fb[i * NF + j] = Mb[i * NF + j] + 0.9f * Pb[i * NF + j] + acc[r];
    }
}

// ---------------------------------------------------------------------------
// K4: weit[b,n,m] = sigmoid(dot(feat_edge[b,n,m,:], query[b,:])) * F[b,n,m]
// (final_mask fused in -> k_out reads one matrix instead of two)
// One wave per chunk of 32 consecutive (b,n,m). d=256 = 64 lanes x float4
// -> one coalesced 1024B wave-load per element. Memory-bound (512 MiB read).
// ---------------------------------------------------------------------------
__global__ __launch_bounds__(256) void k_weit(const float* __restrict__ fe,
                                              const float* __restrict__ query,
                                              const float* __restrict__ F,
                                              float* __restrict__ weit) {
    const int lane = threadIdx.x & 63;
    const int wave = blockIdx.x * 4 + (threadIdx.x >> 6);
    const int e0 = wave * 32;          // 524288 elements total, chunks of 32
    const int b = e0 >> 14;            // 16384 elements per batch
    const float4 q = ((const float4*)(query + (size_t)b * DE))[lane];
    const float4* fv = (const float4*)(fe + (size_t)e0 * DE);
    #pragma unroll 4
    for (int c = 0; c < 32; ++c) {
        float4 f = fv[(size_t)c * 64 + lane];
        float acc = f.x * q.x + f.y * q.y + f.z * q.z + f.w * q.w;
        #pragma unroll
        for (int m = 32; m; m >>= 1) acc += __shfl_xor(acc, m, 64);
        if (lane == 0) {
            const float s = 1.0f / (1.0f + __expf(-acc));
            weit[e0 + c] = s * F[e0 + c];
        }
    }
}

// ---------------------------------------------------------------------------
// K5: att_in = einsum(att_stack, stack_ptr); att_out = einsum(att_in, W');
// norm by m-max; blend into att_stack_new; write all 4 outputs.
// One 512-thread block per batch; n-loop split over 2 halves (h) with LDS
// combine so 8 waves keep loads in flight.
// ---------------------------------------------------------------------------
__global__ __launch_bounds__(512) void k_out(const float* __restrict__ att_stack,
                                             const float* __restrict__ stack_ptr,
                                             const float* __restrict__ W,
                                             float* __restrict__ out) {
    __shared__ float sps[SL];
    __shared__ float att_in[G * NF];
    __shared__ float part[G][2][NF];
    __shared__ float redmax[4];
    const int b = blockIdx.x;
    const int t = threadIdx.x;
    if (t < SL) sps[t] = stack_ptr[b * SL + t];
    __syncthreads();
    if (t < 256) {   // att_in[b,n,g] = sum_s att_stack[b,n,g,s] * sp[s]
        const int n = t >> 1, g = t & 1;
        const float4* as = (const float4*)(att_stack + ((size_t)(b * NF + n) * G + g) * SL);
        float4 a0 = as[0], a1 = as[1];
        att_in[g * NF + n] = a0.x * sps[0] + a0.y * sps[1] + a0.z * sps[2] + a0.w * sps[3]
                           + a1.x * sps[4] + a1.y * sps[5] + a1.z * sps[6] + a1.w * sps[7];
    }
    __syncthreads();
    const int m = t & 127;
    const int g = (t >> 7) & 1;
    const int h = t >> 8;              // n-half
    const float* Wb = W + (size_t)b * NF * NF;
    const float* ai = att_in + g * NF;
    float acc = 0.0f;
    #pragma unroll 8
    for (int n = h * 64; n < h * 64 + 64; ++n)
        acc += ai[n] * Wb[n * NF + m];
    part[g][h][m] = acc;
    __syncthreads();
    float tot = 0.0f;
    if (h == 0) {
        tot = part[g][0][m] + part[g][1][m];
        float wm = tot;
        #pragma unroll
        for (int mm = 32; mm; mm >>= 1) wm = fmaxf(wm, __shfl_xor(wm, mm, 64));
        if ((t & 63) == 0) redmax[t >> 6] = wm;  // waves 0,1 -> g=0; 2,3 -> g=1
    }
    __syncthreads();
    if (h == 0) {
        float norm = fmaxf(redmax[g * 2], redmax[g * 2 + 1]);
        norm = (norm <= 1.0f) ? 1.0f : norm;
        const float v = tot / norm;
        const size_t base = ((size_t)(b * NF + m) * G + g) * SL;
        const float4* as = (const float4*)(att_stack + base);
        float4 a0 = as[0], a1 = as[1], o0, o1;
        o0.x = v * sps[0] + a0.x * (1.0f - sps[0]);
        o0.y = v * sps[1] + a0.y * (1.0f - sps[1]);
        o0.z = v * sps[2] + a0.z * (1.0f - sps[2]);
        o0.w = v * sps[3] + a0.w * (1.0f - sps[3]);
        o1.x = v * sps[4] + a1.x * (1.0f - sps[4]);
        o1.y = v * sps[5] + a1.y * (1.0f - sps[5]);
        o1.z = v * sps[6] + a1.z * (1.0f - sps[6]);
        o1.w = v * sps[7] + a1.w * (1.0f - sps[7]);
        float4* ov = (float4*)(out + base);
        ov[0] = o0;
        ov[1] = o1;
    }
    // output 1: stack_ptr passthrough
    if (t < SL) out[(size_t)B * NF * G * SL + b * SL + t] = sps[t];
    // outputs 2+3: zeros (2 * DH floats per batch), float4 stores
    if (t < 256) {
        const size_t zbase = (size_t)B * NF * G * SL + B * SL + (size_t)b * 2 * DH;
        ((float4*)(out + zbase))[t] = make_float4(0.f, 0.f, 0.f, 0.f);
    }
}

// ---------------------------------------------------------------------------
extern "C" void kernel_launch(void* const* d_in, const int* in_sizes, int n_in,
                              void* d_out, int out_size, void* d_ws, size_t ws_size,
                              hipStream_t stream) {
    const float* fe        = (const float*)d_in[2];   // feat_edge
    const float* c_i       = (const float*)d_in[3];
    const float* rm        = (const float*)d_in[4];   // relation_mask
    const float* att_stack = (const float*)d_in[5];
    const float* sp        = (const float*)d_in[6];   // stack_ptr
    const float* mcw       = (const float*)d_in[8];   // map_c_w
    const float* mcb       = (const float*)d_in[9];   // map_c_b
    float* out = (float*)d_out;

    float* ws    = (float*)d_ws;
    float* query = ws;                     // 32*256        = 8192
    float* weit  = query + 8192;           // 32*128*128    = 524288
    float* P     = weit + 524288;          // 524288
    float* F     = P + 524288;             // 524288  (total ~6.2 MiB)

    hipLaunchKernelGGL(k_query, dim3(2048), dim3(256), 0, stream, c_i, mcw, mcb, query);
    hipLaunchKernelGGL(k_msq,   dim3(256),  dim3(256), 0, stream, rm, P);
    hipLaunchKernelGGL(k_final, dim3(256),  dim3(256), 0, stream, rm, P, F);
    hipLaunchKernelGGL(k_weit,  dim3(4096), dim3(256), 0, stream, fe, query, F, weit);
    hipLaunchKernelGGL(k_out,   dim3(32),   dim3(512), 0, stream, att_stack, sp, weit, out);
}

// Round 3
// 728.505 us; speedup vs baseline: 1.0025x; 1.0025x over previous
//
#include <hip/hip_runtime.h>
#include <math.h>

#define B 32
#define NF 128
#define DE 256
#define DH 512
#define G 2
#define SL 8

// ---------------------------------------------------------------------------
// K1 (merged): blocks [0,256)  : P = M @ M   (per batch, 16 rows/block)
//              blocks [256,512): query[b,d] = c_i[b,:] . map_c_w[d,:] + b[d]
// Both halves fit the GPU in one pass (2 blocks/CU at 64 KiB LDS).
// ---------------------------------------------------------------------------
__global__ __launch_bounds__(256) void k_qm(const float* __restrict__ c_i,
                                            const float* __restrict__ w,
                                            const float* __restrict__ bias,
                                            const float* __restrict__ rm,
                                            float* __restrict__ query,
                                            float* __restrict__ P) {
    __shared__ float Ms[NF * NF];          // 64 KiB (msq blocks only)
    const int t = threadIdx.x;
    if (blockIdx.x < 256) {
        // ---- msq: P = M @ M ----
        const int b  = blockIdx.x >> 3;
        const int i0 = (blockIdx.x & 7) * 16;
        const float4* src = (const float4*)(rm + (size_t)b * NF * NF);
        float4* dst = (float4*)Ms;
        for (int idx = t; idx < NF * NF / 4; idx += 256) dst[idx] = src[idx];
        __syncthreads();
        const int j  = t & 127;
        const int ig = t >> 7;
        const int ibase = i0 + ig * 8;     // 8 rows per thread
        float acc[8] = {0, 0, 0, 0, 0, 0, 0, 0};
        for (int k = 0; k < NF; k += 4) {
            const float b0 = Ms[(k + 0) * NF + j];
            const float b1 = Ms[(k + 1) * NF + j];
            const float b2 = Ms[(k + 2) * NF + j];
            const float b3 = Ms[(k + 3) * NF + j];
            #pragma unroll
            for (int r = 0; r < 8; ++r) {
                const float4 a = *(const float4*)(Ms + (ibase + r) * NF + k);
                acc[r] += a.x * b0 + a.y * b1 + a.z * b2 + a.w * b3;
            }
        }
        float* Pb = P + (size_t)b * NF * NF;
        #pragma unroll
        for (int r = 0; r < 8; ++r) Pb[(ibase + r) * NF + j] = acc[r];
    } else {
        // ---- query: one wave per 8 outputs (1024 waves, 8192 outputs) ----
        const int wv   = (blockIdx.x - 256) * 4 + (t >> 6);
        const int lane = t & 63;
        const int b    = (wv * 8) >> 8;    // 256 outputs per batch
        const float4* cv = (const float4*)(c_i + (size_t)b * DH);
        const float4 a0 = cv[lane];
        const float4 a1 = cv[64 + lane];
        #pragma unroll
        for (int k = 0; k < 8; ++k) {
            const int o = wv * 8 + k;
            const int d = o & 255;
            const float4* wp = (const float4*)(w + (size_t)d * DH);
            const float4 b0 = wp[lane];
            const float4 b1 = wp[64 + lane];
            float acc = a0.x * b0.x + a0.y * b0.y + a0.z * b0.z + a0.w * b0.w
                      + a1.x * b1.x + a1.y * b1.y + a1.z * b1.z + a1.w * b1.w;
            #pragma unroll
            for (int m = 32; m; m >>= 1) acc += __shfl_xor(acc, m, 64);
            if (lane == 0) query[o] = acc + bias[d];
        }
    }
}

// ---------------------------------------------------------------------------
// K2: F = M + 0.9*P + P @ (0.81*M + 0.729*P)        (P = M^2)
//   = M + 0.9M^2 + 0.81M^3 + 0.729M^4
// ---------------------------------------------------------------------------
__global__ __launch_bounds__(256) void k_final(const float* __restrict__ rm,
                                               const float* __restrict__ P,
                                               float* __restrict__ F) {
    __shared__ float Cs[NF * NF];          // 64 KiB
    const int b  = blockIdx.x >> 3;
    const int i0 = (blockIdx.x & 7) * 16;
    const int t  = threadIdx.x;
    const float* Mb = rm + (size_t)b * NF * NF;
    const float* Pb = P + (size_t)b * NF * NF;
    const float4* mv = (const float4*)Mb;
    const float4* pv = (const float4*)Pb;
    float4* cs4 = (float4*)Cs;
    for (int idx = t; idx < NF * NF / 4; idx += 256) {
        float4 m4 = mv[idx], p4 = pv[idx], c;
        c.x = 0.81f * m4.x + 0.729f * p4.x;
        c.y = 0.81f * m4.y + 0.729f * p4.y;
        c.z = 0.81f * m4.z + 0.729f * p4.z;
        c.w = 0.81f * m4.w + 0.729f * p4.w;
        cs4[idx] = c;
    }
    __syncthreads();
    const int j  = t & 127;
    const int ig = t >> 7;
    const int ibase = i0 + ig * 8;
    float acc[8] = {0, 0, 0, 0, 0, 0, 0, 0};
    for (int k = 0; k < NF; k += 4) {
        const float b0 = Cs[(k + 0) * NF + j];
        const float b1 = Cs[(k + 1) * NF + j];
        const float b2 = Cs[(k + 2) * NF + j];
        const float b3 = Cs[(k + 3) * NF + j];
        #pragma unroll
        for (int r = 0; r < 8; ++r) {
            const float4 a = *(const float4*)(Pb + (size_t)(ibase + r) * NF + k);
            acc[r] += a.x * b0 + a.y * b1 + a.z * b2 + a.w * b3;
        }
    }
    float* Fb = F + (size_t)b * NF * NF;
    #pragma unroll
    for (int r = 0; r < 8; ++r) {
        const int i = ibase + r;
        Fb[i * NF + j] = Mb[i * NF + j] + 0.9f * Pb[i * NF + j] + acc[r];
    }
}

// ---------------------------------------------------------------------------
// K3: weit[b,n,m] = sigmoid(dot(feat_edge[b,n,m,:], query[b,:])) * F[b,n,m]
// One wave per chunk of 32 consecutive (b,n,m); d=256 = 64 lanes x float4.
// Memory-bound: 512 MiB compulsory read of feat_edge — this is the roofline.
// ---------------------------------------------------------------------------
__global__ __launch_bounds__(256) void k_weit(const float* __restrict__ fe,
                                              const float* __restrict__ query,
                                              const float* __restrict__ F,
                                              float* __restrict__ weit) {
    const int lane = threadIdx.x & 63;
    const int wave = blockIdx.x * 4 + (threadIdx.x >> 6);
    const int e0 = wave * 32;          // 524288 elements total, chunks of 32
    const int b = e0 >> 14;            // 16384 elements per batch
    const float4 q = ((const float4*)(query + (size_t)b * DE))[lane];
    const float4* fv = (const float4*)(fe + (size_t)e0 * DE);
    #pragma unroll 4
    for (int c = 0; c < 32; ++c) {
        float4 f = fv[(size_t)c * 64 + lane];
        float acc = f.x * q.x + f.y * q.y + f.z * q.z + f.w * q.w;
        #pragma unroll
        for (int m = 32; m; m >>= 1) acc += __shfl_xor(acc, m, 64);
        if (lane == 0) {
            const float s = 1.0f / (1.0f + __expf(-acc));
            weit[e0 + c] = s * F[e0 + c];
        }
    }
}

// ---------------------------------------------------------------------------
// K4: att_in = einsum(att_stack, stack_ptr); att_out = einsum(att_in, W');
// norm by m-max; blend into att_stack_new; write all 4 outputs.
// One 512-thread block per batch; n-loop split over 2 halves (h).
// ---------------------------------------------------------------------------
__global__ __launch_bounds__(512) void k_out(const float* __restrict__ att_stack,
                                             const float* __restrict__ stack_ptr,
                                             const float* __restrict__ W,
                                             float* __restrict__ out) {
    __shared__ float sps[SL];
    __shared__ float att_in[G * NF];
    __shared__ float part[G][2][NF];
    __shared__ float redmax[4];
    const int b = blockIdx.x;
    const int t = threadIdx.x;
    if (t < SL) sps[t] = stack_ptr[b * SL + t];
    __syncthreads();
    if (t < 256) {   // att_in[b,n,g] = sum_s att_stack[b,n,g,s] * sp[s]
        const int n = t >> 1, g = t & 1;
        const float4* as = (const float4*)(att_stack + ((size_t)(b * NF + n) * G + g) * SL);
        float4 a0 = as[0], a1 = as[1];
        att_in[g * NF + n] = a0.x * sps[0] + a0.y * sps[1] + a0.z * sps[2] + a0.w * sps[3]
                           + a1.x * sps[4] + a1.y * sps[5] + a1.z * sps[6] + a1.w * sps[7];
    }
    __syncthreads();
    const int m = t & 127;
    const int g = (t >> 7) & 1;
    const int h = t >> 8;              // n-half
    const float* Wb = W + (size_t)b * NF * NF;
    const float* ai = att_in + g * NF;
    float acc = 0.0f;
    #pragma unroll 8
    for (int n = h * 64; n < h * 64 + 64; ++n)
        acc += ai[n] * Wb[n * NF + m];
    part[g][h][m] = acc;
    __syncthreads();
    float tot = 0.0f;
    if (h == 0) {
        tot = part[g][0][m] + part[g][1][m];
        float wm = tot;
        #pragma unroll
        for (int mm = 32; mm; mm >>= 1) wm = fmaxf(wm, __shfl_xor(wm, mm, 64));
        if ((t & 63) == 0) redmax[t >> 6] = wm;  // waves 0,1 -> g=0; 2,3 -> g=1
    }
    __syncthreads();
    if (h == 0) {
        float norm = fmaxf(redmax[g * 2], redmax[g * 2 + 1]);
        norm = (norm <= 1.0f) ? 1.0f : norm;
        const float v = tot / norm;
        const size_t base = ((size_t)(b * NF + m) * G + g) * SL;
        const float4* as = (const float4*)(att_stack + base);
        float4 a0 = as[0], a1 = as[1], o0, o1;
        o0.x = v * sps[0] + a0.x * (1.0f - sps[0]);
        o0.y = v * sps[1] + a0.y * (1.0f - sps[1]);
        o0.z = v * sps[2] + a0.z * (1.0f - sps[2]);
        o0.w = v * sps[3] + a0.w * (1.0f - sps[3]);
        o1.x = v * sps[4] + a1.x * (1.0f - sps[4]);
        o1.y = v * sps[5] + a1.y * (1.0f - sps[5]);
        o1.z = v * sps[6] + a1.z * (1.0f - sps[6]);
        o1.w = v * sps[7] + a1.w * (1.0f - sps[7]);
        float4* ov = (float4*)(out + base);
        ov[0] = o0;
        ov[1] = o1;
    }
    // output 1: stack_ptr passthrough
    if (t < SL) out[(size_t)B * NF * G * SL + b * SL + t] = sps[t];
    // outputs 2+3: zeros (2 * DH floats per batch), float4 stores
    if (t < 256) {
        const size_t zbase = (size_t)B * NF * G * SL + B * SL + (size_t)b * 2 * DH;
        ((float4*)(out + zbase))[t] = make_float4(0.f, 0.f, 0.f, 0.f);
    }
}

// ---------------------------------------------------------------------------
extern "C" void kernel_launch(void* const* d_in, const int* in_sizes, int n_in,
                              void* d_out, int out_size, void* d_ws, size_t ws_size,
                              hipStream_t stream) {
    const float* fe        = (const float*)d_in[2];   // feat_edge
    const float* c_i       = (const float*)d_in[3];
    const float* rm        = (const float*)d_in[4];   // relation_mask
    const float* att_stack = (const float*)d_in[5];
    const float* sp        = (const float*)d_in[6];   // stack_ptr
    const float* mcw       = (const float*)d_in[8];   // map_c_w
    const float* mcb       = (const float*)d_in[9];   // map_c_b
    float* out = (float*)d_out;

    float* ws    = (float*)d_ws;
    float* query = ws;                     // 32*256        = 8192
    float* weit  = query + 8192;           // 32*128*128    = 524288
    float* P     = weit + 524288;          // 524288
    float* F     = P + 524288;             // 524288  (total ~6.2 MiB)

    hipLaunchKernelGGL(k_qm,    dim3(512),  dim3(256), 0, stream, c_i, mcw, mcb, rm, query, P);
    hipLaunchKernelGGL(k_final, dim3(256),  dim3(256), 0, stream, rm, P, F);
    hipLaunchKernelGGL(k_weit,  dim3(4096), dim3(256), 0, stream, fe, query, F, weit);
    hipLaunchKernelGGL(k_out,   dim3(32),   dim3(512), 0, stream, att_stack, sp, weit, out);
}